// Round 1
// baseline (73.593 us; speedup 1.0000x reference)
//
#include <hip/hip_runtime.h>

// Tensorized (tensor-train) embedding, vocab 32000 = 8*10*20*20, out 768 = 4*4*6*8,
// ranks (1,16,16,16,1). B = 8*4096 = 32768 tokens, fp32 output.
//
// Strategy: precompute pairwise contractions
//   G01[d0*10+d1][a][r2]   (a = a0*4+m1, 16x16)        -> 80  * 256 floats = 80 KB
//   G23[d2*20+d3][r2][mc]  (mc = m2*8+m3, 16x48)       -> 400 * 768 floats = 1.2 MB
// then per token:  out[a][mc] = sum_r2 G01[a][r2] * G23[r2][mc]   (12288 FMA/token)
// One wave per token; each lane writes 3 coalesced float4s.

#define NTOK   32768
#define G01_BYTES (8 * 10 * 256 * 4)        // 81920
#define G23_BYTES (20 * 20 * 768 * 4)       // 1228800
#define WS_NEED   (G01_BYTES + G23_BYTES)   // 1310720

__global__ void precompute_g01(const float* __restrict__ core0,
                               const float* __restrict__ core1,
                               float* __restrict__ g01) {
    int combo = blockIdx.x;                 // d0*10 + d1, 80 blocks
    int d0 = combo / 10, d1 = combo % 10;
    int t = threadIdx.x;                    // 256 = a(16) * r2(16)
    int a = t >> 4, r2 = t & 15;
    int a0 = a >> 2, m1 = a & 3;
    float acc = 0.f;
#pragma unroll
    for (int r1 = 0; r1 < 16; ++r1) {
        float c0 = core0[(d0 * 4 + a0) * 16 + r1];               // [1,8,4,16]
        float c1 = core1[((r1 * 10 + d1) * 4 + m1) * 16 + r2];   // [16,10,4,16]
        acc += c0 * c1;
    }
    g01[combo * 256 + t] = acc;
}

__global__ void precompute_g23(const float* __restrict__ core2,
                               const float* __restrict__ core3,
                               float* __restrict__ g23) {
    int combo = blockIdx.x;                 // d2*20 + d3, 400 blocks
    int d2 = combo / 20, d3 = combo % 20;
    int t = threadIdx.x;                    // 256 threads, 3 elems each
#pragma unroll
    for (int i = 0; i < 3; ++i) {
        int flat = t + i * 256;             // [0,768) = r2(16) * mc(48)
        int r2 = flat / 48, mc = flat % 48;
        int m2 = mc >> 3, m3 = mc & 7;
        float acc = 0.f;
#pragma unroll
        for (int r3 = 0; r3 < 16; ++r3) {
            float c2 = core2[((r2 * 20 + d2) * 6 + m2) * 16 + r3];  // [16,20,6,16]
            float c3 = core3[(r3 * 20 + d3) * 8 + m3];              // [16,20,8,1]
            acc += c2 * c3;
        }
        g23[combo * 768 + flat] = acc;
    }
}

__global__ __launch_bounds__(256) void te_main(const int* __restrict__ x,
                                               const float* __restrict__ g01,
                                               const float* __restrict__ g23,
                                               float* __restrict__ out) {
    int wave = threadIdx.x >> 6;            // 4 waves/block, 1 token/wave
    int lane = threadIdx.x & 63;
    int tok = blockIdx.x * 4 + wave;
    int idx = x[tok];
    int d0 = idx / 4000;
    int rem = idx - d0 * 4000;
    int d1 = rem / 400;
    rem -= d1 * 400;
    int d2 = rem / 20;
    int d3 = rem - d2 * 20;

    const float* __restrict__ G1 = g01 + (d0 * 10 + d1) * 256;   // [16][16]
    const float* __restrict__ G2 = g23 + (d2 * 20 + d3) * 768;   // [16][48]
    float* __restrict__ o = out + (size_t)tok * 768;

#pragma unroll
    for (int p = 0; p < 3; ++p) {
        int base = (p * 64 + lane) * 4;     // float4 index over [0,768)
        int a = base / 48;                  // output row (16 rows of 48)
        int mc = base - a * 48;             // col within row, multiple of 4
        const float4* g1v = (const float4*)(G1 + a * 16);
        float4 ca = g1v[0], cb = g1v[1], cc = g1v[2], cd = g1v[3];
        float s[16] = {ca.x, ca.y, ca.z, ca.w, cb.x, cb.y, cb.z, cb.w,
                       cc.x, cc.y, cc.z, cc.w, cd.x, cd.y, cd.z, cd.w};
        float4 acc = {0.f, 0.f, 0.f, 0.f};
#pragma unroll
        for (int r2 = 0; r2 < 16; ++r2) {
            float4 v = *(const float4*)(G2 + r2 * 48 + mc);
            acc.x += s[r2] * v.x;
            acc.y += s[r2] * v.y;
            acc.z += s[r2] * v.z;
            acc.w += s[r2] * v.w;
        }
        *(float4*)(o + base) = acc;
    }
}

// Slow correct fallback if the workspace is too small for the tables.
__global__ void te_direct(const int* __restrict__ x,
                          const float* __restrict__ core0,
                          const float* __restrict__ core1,
                          const float* __restrict__ core2,
                          const float* __restrict__ core3,
                          float* __restrict__ out) {
    int tok = blockIdx.x;
    int lane = threadIdx.x;                 // 64
    int idx = x[tok];
    int d0 = idx / 4000;
    int rem = idx - d0 * 4000;
    int d1 = rem / 400;
    rem -= d1 * 400;
    int d2 = rem / 20;
    int d3 = rem - d2 * 20;
    float* o = out + (size_t)tok * 768;

    for (int p = 0; p < 3; ++p) {
        int base = (p * 64 + lane) * 4;
        int a = base / 48;
        int mc = base - a * 48;
        int a0 = a >> 2, m1 = a & 3;
        float s[16];
#pragma unroll
        for (int r2 = 0; r2 < 16; ++r2) {
            float acc = 0.f;
            for (int r1 = 0; r1 < 16; ++r1)
                acc += core0[(d0 * 4 + a0) * 16 + r1] *
                       core1[((r1 * 10 + d1) * 4 + m1) * 16 + r2];
            s[r2] = acc;
        }
        float4 accv = {0.f, 0.f, 0.f, 0.f};
        float* accp = (float*)&accv;
        for (int j = 0; j < 4; ++j) {
            int mcj = mc + j;
            int m2 = mcj >> 3, m3 = mcj & 7;
            float t = 0.f;
            for (int r2 = 0; r2 < 16; ++r2) {
                float g = 0.f;
                for (int r3 = 0; r3 < 16; ++r3)
                    g += core2[((r2 * 20 + d2) * 6 + m2) * 16 + r3] *
                         core3[(r3 * 20 + d3) * 8 + m3];
                t += s[r2] * g;
            }
            accp[j] = t;
        }
        *(float4*)(o + base) = accv;
    }
}

extern "C" void kernel_launch(void* const* d_in, const int* in_sizes, int n_in,
                              void* d_out, int out_size, void* d_ws, size_t ws_size,
                              hipStream_t stream) {
    const int*   x     = (const int*)d_in[0];
    const float* core0 = (const float*)d_in[1];
    const float* core1 = (const float*)d_in[2];
    const float* core2 = (const float*)d_in[3];
    const float* core3 = (const float*)d_in[4];
    float* out = (float*)d_out;

    if (ws_size >= (size_t)WS_NEED) {
        float* g01 = (float*)d_ws;
        float* g23 = (float*)((char*)d_ws + G01_BYTES);
        precompute_g01<<<80, 256, 0, stream>>>(core0, core1, g01);
        precompute_g23<<<400, 256, 0, stream>>>(core2, core3, g23);
        te_main<<<NTOK / 4, 256, 0, stream>>>(x, g01, g23, out);
    } else {
        te_direct<<<NTOK, 64, 0, stream>>>(x, core0, core1, core2, core3, out);
    }
}

// Round 2
// 67.338 us; speedup vs baseline: 1.0929x; 1.0929x over previous
//
#include <hip/hip_runtime.h>

// Tensorized (tensor-train) embedding. vocab 32000 = 8*10*20*20, out 768,
// ranks (1,16,16,16,1), B = 32768 tokens, fp32 out.
//
// G01[c01][a][r2]  c01 = idx/400  (80 combos  x 256 floats =  80 KB)
// G23[c23][r2][mc] c23 = idx%400  (400 combos x 768 floats = 1.2 MB)
// out[tok][a*48+mc] = sum_r2 G01[a][r2] * G23[r2][mc]
//
// Tokens are counting-sorted by c23 so each block stages its combo's 3 KB
// G23 slice in LDS once; per token-wave only 16 global VMEM instrs remain.

#define NTOK   32768
#define NBKT   400
#define SPLIT  4

#define G01_BYTES  (80 * 256 * 4)            // 81920
#define G23_BYTES  (400 * 768 * 4)           // 1228800
#define TBL_BYTES  (G01_BYTES + G23_BYTES)   // 1310720
#define LIST_BYTES (NTOK * 8)                // 262144
#define META_INTS  (NBKT + NBKT + NBKT + 1)  // counts, cursors, offsets[401]
#define FULL_NEED  (TBL_BYTES + LIST_BYTES + META_INTS * 4)

__global__ void precompute_g01(const float* __restrict__ core0,
                               const float* __restrict__ core1,
                               float* __restrict__ g01,
                               int* __restrict__ counts, int* __restrict__ cursors) {
    int combo = blockIdx.x;                 // c01 = d0*10 + d1, 80 blocks
    int t = threadIdx.x;                    // 256 = a(16) * r2(16)
    if (combo < 2) {                        // fused meta zeroing (512 >= 400)
        int z = combo * 256 + t;
        if (z < NBKT) { counts[z] = 0; cursors[z] = 0; }
    }
    int d0 = combo / 10, d1 = combo % 10;
    int a = t >> 4, r2 = t & 15;
    int a0 = a >> 2, m1 = a & 3;
    float acc = 0.f;
#pragma unroll
    for (int r1 = 0; r1 < 16; ++r1) {
        float c0 = core0[(d0 * 4 + a0) * 16 + r1];               // [1,8,4,16]
        float c1 = core1[((r1 * 10 + d1) * 4 + m1) * 16 + r2];   // [16,10,4,16]
        acc += c0 * c1;
    }
    g01[combo * 256 + t] = acc;
}

__global__ void precompute_g23(const float* __restrict__ core2,
                               const float* __restrict__ core3,
                               float* __restrict__ g23,
                               const int* __restrict__ x, int* __restrict__ counts) {
    int combo = blockIdx.x;                 // c23 = d2*20 + d3, 400 blocks
    int t = threadIdx.x;
    int g = blockIdx.x * 256 + t;           // fused histogram (102400 >= 32768)
    if (g < NTOK) atomicAdd(&counts[x[g] % NBKT], 1);
    int d2 = combo / 20, d3 = combo % 20;
#pragma unroll
    for (int i = 0; i < 3; ++i) {
        int flat = t + i * 256;             // [0,768) = r2(16) * mc(48)
        int r2 = flat / 48, mc = flat % 48;
        int m2 = mc >> 3, m3 = mc & 7;
        float acc = 0.f;
#pragma unroll
        for (int r3 = 0; r3 < 16; ++r3) {
            float c2 = core2[((r2 * 20 + d2) * 6 + m2) * 16 + r3];  // [16,20,6,16]
            float c3 = core3[(r3 * 20 + d3) * 8 + m3];              // [16,20,8,1]
            acc += c2 * c3;
        }
        g23[combo * 768 + flat] = acc;
    }
}

__global__ void scan_k(const int* __restrict__ counts, int* __restrict__ offsets) {
    __shared__ int s[512];
    int t = threadIdx.x;
    s[t] = (t < NBKT) ? counts[t] : 0;
    __syncthreads();
    for (int off = 1; off < 512; off <<= 1) {
        int w = (t >= off) ? s[t - off] : 0;
        __syncthreads();
        s[t] += w;
        __syncthreads();
    }
    if (t == 0) offsets[0] = 0;
    if (t < NBKT) offsets[t + 1] = s[t];
}

__global__ void scatter_k(const int* __restrict__ x, const int* __restrict__ offsets,
                          int* __restrict__ cursors, int2* __restrict__ list) {
    int t = blockIdx.x * 256 + threadIdx.x;
    if (t >= NTOK) return;
    int idx = x[t];
    int b = idx % NBKT;
    int pos = offsets[b] + atomicAdd(&cursors[b], 1);
    list[pos] = make_int2(t, (idx / NBKT) * 256);   // token, g01 byte-row base
}

__global__ __launch_bounds__(256) void te_bucket(const int2* __restrict__ list,
                                                 const int* __restrict__ offsets,
                                                 const float* __restrict__ g01,
                                                 const float* __restrict__ g23,
                                                 float* __restrict__ out) {
    __shared__ float lds[768];
    int combo = blockIdx.x / SPLIT;
    int part  = blockIdx.x % SPLIT;
    int t = threadIdx.x;
    if (t < 192)
        ((float4*)lds)[t] = ((const float4*)(g23 + combo * 768))[t];
    __syncthreads();

    int beg = offsets[combo], end = offsets[combo + 1];
    int n = end - beg;
    int chunk = (n + SPLIT - 1) / SPLIT;
    int lo = beg + part * chunk;
    int hi = lo + chunk; if (hi > end) hi = end;

    int wave = t >> 6, lane = t & 63;
    for (int i = lo + wave; i < hi; i += 4) {
        int2 e = list[i];
        const float* __restrict__ G1 = g01 + e.y;      // [16][16]
        float* __restrict__ o = out + (size_t)e.x * 768;
#pragma unroll
        for (int p = 0; p < 3; ++p) {
            int base = (p * 64 + lane) * 4;            // float4 pos in [0,768)
            int a = base / 48;
            int mc = base - a * 48;
            const float4* g1v = (const float4*)(G1 + a * 16);
            float4 ca = g1v[0], cb = g1v[1], cc = g1v[2], cd = g1v[3];
            float s[16] = {ca.x, ca.y, ca.z, ca.w, cb.x, cb.y, cb.z, cb.w,
                           cc.x, cc.y, cc.z, cc.w, cd.x, cd.y, cd.z, cd.w};
            float4 acc = {0.f, 0.f, 0.f, 0.f};
#pragma unroll
            for (int r2 = 0; r2 < 16; ++r2) {
                float4 v = *(const float4*)(lds + r2 * 48 + mc);
                acc.x += s[r2] * v.x;
                acc.y += s[r2] * v.y;
                acc.z += s[r2] * v.z;
                acc.w += s[r2] * v.w;
            }
            *(float4*)(o + base) = acc;
        }
    }
}

// ---- fallback tiers (no bucketing) ----

__global__ void precompute_g01_nf(const float* __restrict__ core0,
                                  const float* __restrict__ core1,
                                  float* __restrict__ g01) {
    int combo = blockIdx.x;
    int t = threadIdx.x;
    int d0 = combo / 10, d1 = combo % 10;
    int a = t >> 4, r2 = t & 15;
    int a0 = a >> 2, m1 = a & 3;
    float acc = 0.f;
#pragma unroll
    for (int r1 = 0; r1 < 16; ++r1)
        acc += core0[(d0 * 4 + a0) * 16 + r1] *
               core1[((r1 * 10 + d1) * 4 + m1) * 16 + r2];
    g01[combo * 256 + t] = acc;
}

__global__ void precompute_g23_nf(const float* __restrict__ core2,
                                  const float* __restrict__ core3,
                                  float* __restrict__ g23) {
    int combo = blockIdx.x;
    int t = threadIdx.x;
    int d2 = combo / 20, d3 = combo % 20;
#pragma unroll
    for (int i = 0; i < 3; ++i) {
        int flat = t + i * 256;
        int r2 = flat / 48, mc = flat % 48;
        int m2 = mc >> 3, m3 = mc & 7;
        float acc = 0.f;
#pragma unroll
        for (int r3 = 0; r3 < 16; ++r3)
            acc += core2[((r2 * 20 + d2) * 6 + m2) * 16 + r3] *
                   core3[(r3 * 20 + d3) * 8 + m3];
        g23[combo * 768 + flat] = acc;
    }
}

__global__ __launch_bounds__(256) void te_main(const int* __restrict__ x,
                                               const float* __restrict__ g01,
                                               const float* __restrict__ g23,
                                               float* __restrict__ out) {
    int wave = threadIdx.x >> 6;
    int lane = threadIdx.x & 63;
    int tok = blockIdx.x * 4 + wave;
    int idx = x[tok];
    const float* __restrict__ G1 = g01 + (idx / 400) * 256;
    const float* __restrict__ G2 = g23 + (idx % 400) * 768;
    float* __restrict__ o = out + (size_t)tok * 768;
#pragma unroll
    for (int p = 0; p < 3; ++p) {
        int base = (p * 64 + lane) * 4;
        int a = base / 48;
        int mc = base - a * 48;
        const float4* g1v = (const float4*)(G1 + a * 16);
        float4 ca = g1v[0], cb = g1v[1], cc = g1v[2], cd = g1v[3];
        float s[16] = {ca.x, ca.y, ca.z, ca.w, cb.x, cb.y, cb.z, cb.w,
                       cc.x, cc.y, cc.z, cc.w, cd.x, cd.y, cd.z, cd.w};
        float4 acc = {0.f, 0.f, 0.f, 0.f};
#pragma unroll
        for (int r2 = 0; r2 < 16; ++r2) {
            float4 v = *(const float4*)(G2 + r2 * 48 + mc);
            acc.x += s[r2] * v.x;
            acc.y += s[r2] * v.y;
            acc.z += s[r2] * v.z;
            acc.w += s[r2] * v.w;
        }
        *(float4*)(o + base) = acc;
    }
}

__global__ void te_direct(const int* __restrict__ x,
                          const float* __restrict__ core0,
                          const float* __restrict__ core1,
                          const float* __restrict__ core2,
                          const float* __restrict__ core3,
                          float* __restrict__ out) {
    int tok = blockIdx.x;
    int lane = threadIdx.x;
    int idx = x[tok];
    int d0 = idx / 4000;
    int rem = idx - d0 * 4000;
    int d1 = rem / 400;
    rem -= d1 * 400;
    int d2 = rem / 20;
    int d3 = rem - d2 * 20;
    float* o = out + (size_t)tok * 768;
    for (int p = 0; p < 3; ++p) {
        int base = (p * 64 + lane) * 4;
        int a = base / 48;
        int mc = base - a * 48;
        int a0 = a >> 2, m1 = a & 3;
        float s[16];
#pragma unroll
        for (int r2 = 0; r2 < 16; ++r2) {
            float acc = 0.f;
            for (int r1 = 0; r1 < 16; ++r1)
                acc += core0[(d0 * 4 + a0) * 16 + r1] *
                       core1[((r1 * 10 + d1) * 4 + m1) * 16 + r2];
            s[r2] = acc;
        }
        float4 accv = {0.f, 0.f, 0.f, 0.f};
        float* accp = (float*)&accv;
        for (int j = 0; j < 4; ++j) {
            int mcj = mc + j;
            int m2 = mcj >> 3, m3 = mcj & 7;
            float tt = 0.f;
            for (int r2 = 0; r2 < 16; ++r2) {
                float g = 0.f;
                for (int r3 = 0; r3 < 16; ++r3)
                    g += core2[((r2 * 20 + d2) * 6 + m2) * 16 + r3] *
                         core3[(r3 * 20 + d3) * 8 + m3];
                tt += s[r2] * g;
            }
            accp[j] = tt;
        }
        *(float4*)(o + base) = accv;
    }
}

extern "C" void kernel_launch(void* const* d_in, const int* in_sizes, int n_in,
                              void* d_out, int out_size, void* d_ws, size_t ws_size,
                              hipStream_t stream) {
    const int*   x     = (const int*)d_in[0];
    const float* core0 = (const float*)d_in[1];
    const float* core1 = (const float*)d_in[2];
    const float* core2 = (const float*)d_in[3];
    const float* core3 = (const float*)d_in[4];
    float* out = (float*)d_out;

    if (ws_size >= (size_t)FULL_NEED) {
        char* base = (char*)d_ws;
        float* g01    = (float*)base;
        float* g23    = (float*)(base + G01_BYTES);
        int2*  list   = (int2*)(base + TBL_BYTES);
        int*   counts = (int*)(base + TBL_BYTES + LIST_BYTES);
        int*   cursors = counts + NBKT;
        int*   offsets = cursors + NBKT;

        precompute_g01<<<80, 256, 0, stream>>>(core0, core1, g01, counts, cursors);
        precompute_g23<<<400, 256, 0, stream>>>(core2, core3, g23, x, counts);
        scan_k<<<1, 512, 0, stream>>>(counts, offsets);
        scatter_k<<<NTOK / 256, 256, 0, stream>>>(x, offsets, cursors, list);
        te_bucket<<<NBKT * SPLIT, 256, 0, stream>>>(list, offsets, g01, g23, out);
    } else if (ws_size >= (size_t)TBL_BYTES) {
        float* g01 = (float*)d_ws;
        float* g23 = (float*)((char*)d_ws + G01_BYTES);
        precompute_g01_nf<<<80, 256, 0, stream>>>(core0, core1, g01);
        precompute_g23_nf<<<400, 256, 0, stream>>>(core2, core3, g23);
        te_main<<<NTOK / 4, 256, 0, stream>>>(x, g01, g23, out);
    } else {
        te_direct<<<NTOK, 64, 0, stream>>>(x, core0, core1, core2, core3, out);
    }
}

// Round 3
// 52.272 us; speedup vs baseline: 1.4079x; 1.2882x over previous
//
#include <hip/hip_runtime.h>

// Tensorized (tensor-train) embedding. vocab 32000 = 8*10*20*20, out 768,
// ranks (1,16,16,16,1), B = 32768 tokens, fp32 out.
//
// G01[c01][a][r2]  c01 = idx/400  (80 combos  x 256 floats =  80 KB)
// G23[c23][r2][mc] c23 = idx%400  (400 combos x 768 floats = 1.2 MB)
// out[tok][a*48+mc] = sum_r2 G01[a][r2] * G23[r2][mc]
//
// 3-kernel pipeline: (A) build tables + zero counters, (B) slotted bucket
// scatter (no histogram/scan), (C) per-bucket blocks stage G23 slice in LDS;
// each wave handles 4 tokens with lane-fixed output row a=lane>>2, col group
// q=lane&3 -> 4 G1 loads + 12 broadcast ds_reads + 3 stores per token.

#define NTOK   32768
#define NBKT   400
#define SLOTS  512
#define SPLIT  2

#define G01_BYTES  (80 * 256 * 4)            // 81920
#define G23_BYTES  (400 * 768 * 4)           // 1228800
#define TBL_BYTES  (G01_BYTES + G23_BYTES)   // 1310720
#define LIST_BYTES (NBKT * SLOTS * 4)        // 819200
#define FULL_NEED  (TBL_BYTES + LIST_BYTES + NBKT * 4)

#define FMA4(A, S, V) { (A).x += (S)*(V).x; (A).y += (S)*(V).y; \
                        (A).z += (S)*(V).z; (A).w += (S)*(V).w; }

// ---- kernel A: tables + zero counters (480 blocks) ----
__global__ void build_tables(const float* __restrict__ core0,
                             const float* __restrict__ core1,
                             const float* __restrict__ core2,
                             const float* __restrict__ core3,
                             float* __restrict__ g01,
                             float* __restrict__ g23,
                             int* __restrict__ cnt) {
    int b = blockIdx.x;
    int t = threadIdx.x;
    if (b < 2) {                            // zero 400 counters
        int z = b * 256 + t;
        if (z < NBKT) cnt[z] = 0;
    }
    if (b < NBKT) {                         // G23 combo
        int d2 = b / 20, d3 = b % 20;
#pragma unroll
        for (int i = 0; i < 3; ++i) {
            int flat = t + i * 256;         // [0,768) = r2(16) * mc(48)
            int r2 = flat / 48, mc = flat % 48;
            int m2 = mc >> 3, m3 = mc & 7;
            float acc = 0.f;
#pragma unroll
            for (int r3 = 0; r3 < 16; ++r3) {
                float c2 = core2[((r2 * 20 + d2) * 6 + m2) * 16 + r3]; // [16,20,6,16]
                float c3 = core3[(r3 * 20 + d3) * 8 + m3];             // [16,20,8,1]
                acc += c2 * c3;
            }
            g23[b * 768 + flat] = acc;
        }
    } else {                                // G01 combo
        int combo = b - NBKT;               // 0..79
        int d0 = combo / 10, d1 = combo % 10;
        int a = t >> 4, r2 = t & 15;
        int a0 = a >> 2, m1 = a & 3;
        float acc = 0.f;
#pragma unroll
        for (int r1 = 0; r1 < 16; ++r1) {
            float c0 = core0[(d0 * 4 + a0) * 16 + r1];               // [1,8,4,16]
            float c1 = core1[((r1 * 10 + d1) * 4 + m1) * 16 + r2];   // [16,10,4,16]
            acc += c0 * c1;
        }
        g01[combo * 256 + t] = acc;
    }
}

// ---- kernel B: slotted scatter ----
__global__ void scatter_k(const int* __restrict__ x, int* __restrict__ cnt,
                          int* __restrict__ list) {
    int t = blockIdx.x * 256 + threadIdx.x;
    if (t >= NTOK) return;
    int idx = x[t];
    int b = idx % NBKT;
    int c01 = idx / NBKT;
    int pos = atomicAdd(&cnt[b], 1);
    if (pos < SLOTS) list[b * SLOTS + pos] = t | (c01 << 16);
}

// ---- kernel C: main ----
__global__ __launch_bounds__(256) void te_bucket2(const int* __restrict__ list,
                                                  const int* __restrict__ cnt,
                                                  const float* __restrict__ g01,
                                                  const float* __restrict__ g23,
                                                  float* __restrict__ out) {
    __shared__ float lds[768];
    int combo = blockIdx.x >> 1;            // SPLIT = 2
    int part  = blockIdx.x & 1;
    int t = threadIdx.x;
    if (t < 192)
        ((float4*)lds)[t] = ((const float4*)(g23 + combo * 768))[t];
    __syncthreads();

    int n = cnt[combo]; if (n > SLOTS) n = SLOTS;
    int chunk = (n + 1) >> 1;
    int lo = part * chunk;
    int hi = lo + chunk; if (hi > n) hi = n;
    const int* __restrict__ bl = list + combo * SLOTS;

    int wave = t >> 6, lane = t & 63;
    int a = lane >> 2, q = lane & 3;        // lane owns row a, col group q
    const float* ldsq = lds + q * 4;        // dword base; imm offsets below

    for (int i = lo + wave * 4; i < hi; i += 16) {
        int i1 = i + 1 < hi ? i + 1 : hi - 1;
        int i2 = i + 2 < hi ? i + 2 : hi - 1;
        int i3 = i + 3 < hi ? i + 3 : hi - 1;
        int e[4] = {bl[i], bl[i1], bl[i2], bl[i3]};

        float4 s[4][4];
#pragma unroll
        for (int w = 0; w < 4; ++w) {
            const float4* r = (const float4*)(g01 + (e[w] >> 16) * 256 + a * 16);
            s[w][0] = r[0]; s[w][1] = r[1]; s[w][2] = r[2]; s[w][3] = r[3];
        }

        float4 acc[4][3];
#pragma unroll
        for (int w = 0; w < 4; ++w)
#pragma unroll
            for (int j = 0; j < 3; ++j)
                acc[w][j] = make_float4(0.f, 0.f, 0.f, 0.f);

#pragma unroll
        for (int r4 = 0; r4 < 4; ++r4) {
#pragma unroll
            for (int c = 0; c < 4; ++c) {
                const int r2 = r4 * 4 + c;
                float4 v0 = *(const float4*)(ldsq + r2 * 48);
                float4 v1 = *(const float4*)(ldsq + r2 * 48 + 16);
                float4 v2 = *(const float4*)(ldsq + r2 * 48 + 32);
#pragma unroll
                for (int w = 0; w < 4; ++w) {
                    float sv = (c == 0) ? s[w][r4].x : (c == 1) ? s[w][r4].y
                             : (c == 2) ? s[w][r4].z : s[w][r4].w;
                    FMA4(acc[w][0], sv, v0);
                    FMA4(acc[w][1], sv, v1);
                    FMA4(acc[w][2], sv, v2);
                }
            }
        }

#pragma unroll
        for (int w = 0; w < 4; ++w) {
            if (i + w < hi) {
                float4* o4 = (float4*)(out + (size_t)(e[w] & 0xFFFF) * 768);
                o4[a * 12 + q]     = acc[w][0];
                o4[a * 12 + q + 4] = acc[w][1];
                o4[a * 12 + q + 8] = acc[w][2];
            }
        }
    }
}

// ---- fallback tiers ----

__global__ void precompute_g01_nf(const float* __restrict__ core0,
                                  const float* __restrict__ core1,
                                  float* __restrict__ g01) {
    int combo = blockIdx.x;
    int t = threadIdx.x;
    int d0 = combo / 10, d1 = combo % 10;
    int a = t >> 4, r2 = t & 15;
    int a0 = a >> 2, m1 = a & 3;
    float acc = 0.f;
#pragma unroll
    for (int r1 = 0; r1 < 16; ++r1)
        acc += core0[(d0 * 4 + a0) * 16 + r1] *
               core1[((r1 * 10 + d1) * 4 + m1) * 16 + r2];
    g01[combo * 256 + t] = acc;
}

__global__ void precompute_g23_nf(const float* __restrict__ core2,
                                  const float* __restrict__ core3,
                                  float* __restrict__ g23) {
    int combo = blockIdx.x;
    int t = threadIdx.x;
    int d2 = combo / 20, d3 = combo % 20;
#pragma unroll
    for (int i = 0; i < 3; ++i) {
        int flat = t + i * 256;
        int r2 = flat / 48, mc = flat % 48;
        int m2 = mc >> 3, m3 = mc & 7;
        float acc = 0.f;
#pragma unroll
        for (int r3 = 0; r3 < 16; ++r3)
            acc += core2[((r2 * 20 + d2) * 6 + m2) * 16 + r3] *
                   core3[(r3 * 20 + d3) * 8 + m3];
        g23[combo * 768 + flat] = acc;
    }
}

__global__ __launch_bounds__(256) void te_main(const int* __restrict__ x,
                                               const float* __restrict__ g01,
                                               const float* __restrict__ g23,
                                               float* __restrict__ out) {
    int wave = threadIdx.x >> 6;
    int lane = threadIdx.x & 63;
    int tok = blockIdx.x * 4 + wave;
    int idx = x[tok];
    const float* __restrict__ G1 = g01 + (idx / 400) * 256;
    const float* __restrict__ G2 = g23 + (idx % 400) * 768;
    float* __restrict__ o = out + (size_t)tok * 768;
#pragma unroll
    for (int p = 0; p < 3; ++p) {
        int base = (p * 64 + lane) * 4;
        int a = base / 48;
        int mc = base - a * 48;
        const float4* g1v = (const float4*)(G1 + a * 16);
        float4 ca = g1v[0], cb = g1v[1], cc = g1v[2], cd = g1v[3];
        float s[16] = {ca.x, ca.y, ca.z, ca.w, cb.x, cb.y, cb.z, cb.w,
                       cc.x, cc.y, cc.z, cc.w, cd.x, cd.y, cd.z, cd.w};
        float4 acc = {0.f, 0.f, 0.f, 0.f};
#pragma unroll
        for (int r2 = 0; r2 < 16; ++r2) {
            float4 v = *(const float4*)(G2 + r2 * 48 + mc);
            acc.x += s[r2] * v.x;
            acc.y += s[r2] * v.y;
            acc.z += s[r2] * v.z;
            acc.w += s[r2] * v.w;
        }
        *(float4*)(o + base) = acc;
    }
}

__global__ void te_direct(const int* __restrict__ x,
                          const float* __restrict__ core0,
                          const float* __restrict__ core1,
                          const float* __restrict__ core2,
                          const float* __restrict__ core3,
                          float* __restrict__ out) {
    int tok = blockIdx.x;
    int lane = threadIdx.x;
    int idx = x[tok];
    int d0 = idx / 4000;
    int rem = idx - d0 * 4000;
    int d1 = rem / 400;
    rem -= d1 * 400;
    int d2 = rem / 20;
    int d3 = rem - d2 * 20;
    float* o = out + (size_t)tok * 768;
    for (int p = 0; p < 3; ++p) {
        int base = (p * 64 + lane) * 4;
        int a = base / 48;
        int mc = base - a * 48;
        int a0 = a >> 2, m1 = a & 3;
        float s[16];
#pragma unroll
        for (int r2 = 0; r2 < 16; ++r2) {
            float acc = 0.f;
            for (int r1 = 0; r1 < 16; ++r1)
                acc += core0[(d0 * 4 + a0) * 16 + r1] *
                       core1[((r1 * 10 + d1) * 4 + m1) * 16 + r2];
            s[r2] = acc;
        }
        float4 accv = {0.f, 0.f, 0.f, 0.f};
        float* accp = (float*)&accv;
        for (int j = 0; j < 4; ++j) {
            int mcj = mc + j;
            int m2 = mcj >> 3, m3 = mcj & 7;
            float tt = 0.f;
            for (int r2 = 0; r2 < 16; ++r2) {
                float g = 0.f;
                for (int r3 = 0; r3 < 16; ++r3)
                    g += core2[((r2 * 20 + d2) * 6 + m2) * 16 + r3] *
                         core3[(r3 * 20 + d3) * 8 + m3];
                tt += s[r2] * g;
            }
            accp[j] = tt;
        }
        *(float4*)(o + base) = accv;
    }
}

extern "C" void kernel_launch(void* const* d_in, const int* in_sizes, int n_in,
                              void* d_out, int out_size, void* d_ws, size_t ws_size,
                              hipStream_t stream) {
    const int*   x     = (const int*)d_in[0];
    const float* core0 = (const float*)d_in[1];
    const float* core1 = (const float*)d_in[2];
    const float* core2 = (const float*)d_in[3];
    const float* core3 = (const float*)d_in[4];
    float* out = (float*)d_out;

    if (ws_size >= (size_t)FULL_NEED) {
        char* base = (char*)d_ws;
        float* g01  = (float*)base;
        float* g23  = (float*)(base + G01_BYTES);
        int*   list = (int*)(base + TBL_BYTES);
        int*   cnt  = (int*)(base + TBL_BYTES + LIST_BYTES);

        build_tables<<<NBKT + 80, 256, 0, stream>>>(core0, core1, core2, core3,
                                                    g01, g23, cnt);
        scatter_k<<<NTOK / 256, 256, 0, stream>>>(x, cnt, list);
        te_bucket2<<<NBKT * SPLIT, 256, 0, stream>>>(list, cnt, g01, g23, out);
    } else if (ws_size >= (size_t)TBL_BYTES) {
        float* g01 = (float*)d_ws;
        float* g23 = (float*)((char*)d_ws + G01_BYTES);
        precompute_g01_nf<<<80, 256, 0, stream>>>(core0, core1, g01);
        precompute_g23_nf<<<400, 256, 0, stream>>>(core2, core3, g23);
        te_main<<<NTOK / 4, 256, 0, stream>>>(x, g01, g23, out);
    } else {
        te_direct<<<NTOK, 64, 0, stream>>>(x, core0, core1, core2, core3, out);
    }
}

// Round 4
// 31.363 us; speedup vs baseline: 2.3465x; 1.6667x over previous
//
#include <hip/hip_runtime.h>

// Tensorized (tensor-train) embedding. vocab 32000 = 8*10*20*20, out 768,
// ranks (1,16,16,16,1), B = 32768 tokens, fp32 out.
//
// G01[c01][a][r2]  c01 = idx/400  (80 combos  x 256 floats =  80 KB)
// G23[c23][r2][mc] c23 = idx%400  (400 combos x 768 floats = 1.2 MB)
// out[tok][a*48+mc] = sum_r2 G01[a][r2] * G23[r2][mc]
//
// 2-kernel pipeline: (A) build tables; (B) token-order streaming kernel.
// Each wave owns 8 consecutive tokens with a private 2x3KB LDS double
// buffer: issue token t+1's G23-slice loads (global->reg) BEFORE computing
// token t from LDS, ds_write AFTER (T14 issue-early/write-late). Lane owns
// output row a=lane>>2, col group q=lane&3: 48 broadcast ds_read_b128 +
// 48 FMA4 + 3 coalesced stores per token. Perfectly balanced grid.

#define NTOK   32768
#define TPW    8                              // tokens per wave
#define G01_BYTES  (80 * 256 * 4)             // 81920
#define G23_BYTES  (400 * 768 * 4)            // 1228800
#define TBL_BYTES  (G01_BYTES + G23_BYTES)    // 1310720

#define FMA4(A, S, V) { (A).x += (S)*(V).x; (A).y += (S)*(V).y; \
                        (A).z += (S)*(V).z; (A).w += (S)*(V).w; }

// ---- kernel A: pairwise contraction tables (480 blocks) ----
__global__ void build_tables(const float* __restrict__ core0,
                             const float* __restrict__ core1,
                             const float* __restrict__ core2,
                             const float* __restrict__ core3,
                             float* __restrict__ g01,
                             float* __restrict__ g23) {
    int b = blockIdx.x;
    int t = threadIdx.x;
    if (b < 400) {                          // G23 combo c23 = d2*20+d3
        int d2 = b / 20, d3 = b % 20;
#pragma unroll
        for (int i = 0; i < 3; ++i) {
            int flat = t + i * 256;         // [0,768) = r2(16) * mc(48)
            int r2 = flat / 48, mc = flat % 48;
            int m2 = mc >> 3, m3 = mc & 7;
            float acc = 0.f;
#pragma unroll
            for (int r3 = 0; r3 < 16; ++r3) {
                float c2 = core2[((r2 * 20 + d2) * 6 + m2) * 16 + r3]; // [16,20,6,16]
                float c3 = core3[(r3 * 20 + d3) * 8 + m3];             // [16,20,8,1]
                acc += c2 * c3;
            }
            g23[b * 768 + flat] = acc;
        }
    } else {                                // G01 combo c01 = d0*10+d1
        int combo = b - 400;                // 0..79
        int d0 = combo / 10, d1 = combo % 10;
        int a = t >> 4, r2 = t & 15;
        int a0 = a >> 2, m1 = a & 3;
        float acc = 0.f;
#pragma unroll
        for (int r1 = 0; r1 < 16; ++r1) {
            float c0 = core0[(d0 * 4 + a0) * 16 + r1];               // [1,8,4,16]
            float c1 = core1[((r1 * 10 + d1) * 4 + m1) * 16 + r2];   // [16,10,4,16]
            acc += c0 * c1;
        }
        g01[combo * 256 + t] = acc;
    }
}

// ---- kernel B: token-order streaming main ----
__global__ __launch_bounds__(256) void te_stream(const int* __restrict__ x,
                                                 const float* __restrict__ g01,
                                                 const float* __restrict__ g23,
                                                 float* __restrict__ out) {
    __shared__ float lds[4][2][768];        // [wave][buf][slice] = 24 KB
    const int wave = threadIdx.x >> 6;
    const int lane = threadIdx.x & 63;
    const int gw = blockIdx.x * 4 + wave;   // global wave id
    const int tok0 = gw * TPW;
    const int a = lane >> 2, q = lane & 3;  // lane owns row a, col group q
    float* __restrict__ b0 = lds[wave][0];
    float* __restrict__ b1 = lds[wave][1];

    // all 8 token indices up front (two coalesced int4 loads)
    int4 xa = ((const int4*)(x + tok0))[0];
    int4 xb = ((const int4*)(x + tok0))[1];
    int idxs[TPW] = {xa.x, xa.y, xa.z, xa.w, xb.x, xb.y, xb.z, xb.w};

    // prologue: stage token 0 into buf0, G1 row into regs
    {
        const float4* G2 = (const float4*)(g23 + (idxs[0] % 400) * 768);
        float4 t0 = G2[lane], t1 = G2[lane + 64], t2 = G2[lane + 128];
        ((float4*)b0)[lane] = t0;
        ((float4*)b0)[lane + 64] = t1;
        ((float4*)b0)[lane + 128] = t2;
    }
    const float4* g1p = (const float4*)(g01 + (idxs[0] / 400) * 256 + a * 16);
    float4 s0 = g1p[0], s1 = g1p[1], s2 = g1p[2], s3 = g1p[3];

#pragma unroll
    for (int t = 0; t < TPW; ++t) {
        float* cur = (t & 1) ? b1 : b0;
        float* nxt = (t & 1) ? b0 : b1;

        // (1) issue next token's global loads EARLY (latency hides under compute)
        float4 n0, n1, n2, m0, m1, m2, m3;
        if (t + 1 < TPW) {
            const float4* G2n = (const float4*)(g23 + (idxs[t + 1] % 400) * 768);
            n0 = G2n[lane]; n1 = G2n[lane + 64]; n2 = G2n[lane + 128];
            const float4* g1n = (const float4*)(g01 + (idxs[t + 1] / 400) * 256 + a * 16);
            m0 = g1n[0]; m1 = g1n[1]; m2 = g1n[2]; m3 = g1n[3];
        }

        // (2) compute token t from LDS (48 broadcast ds_read_b128, conflict-free)
        const float* cq = cur + q * 4;
        float4 sarr[4] = {s0, s1, s2, s3};
        float4 acc0 = {0.f,0.f,0.f,0.f}, acc1 = {0.f,0.f,0.f,0.f}, acc2 = {0.f,0.f,0.f,0.f};
#pragma unroll
        for (int rr = 0; rr < 4; ++rr) {
#pragma unroll
            for (int c = 0; c < 4; ++c) {
                const int r2 = rr * 4 + c;
                float4 v0 = *(const float4*)(cq + r2 * 48);
                float4 v1 = *(const float4*)(cq + r2 * 48 + 16);
                float4 v2 = *(const float4*)(cq + r2 * 48 + 32);
                float sv = (c == 0) ? sarr[rr].x : (c == 1) ? sarr[rr].y
                         : (c == 2) ? sarr[rr].z : sarr[rr].w;
                FMA4(acc0, sv, v0);
                FMA4(acc1, sv, v1);
                FMA4(acc2, sv, v2);
            }
        }

        // (3) store token t (row-contiguous across the wave; tokens sequential)
        float4* o4 = (float4*)(out + (size_t)(tok0 + t) * 768);
        o4[a * 12 + q]     = acc0;
        o4[a * 12 + q + 4] = acc1;
        o4[a * 12 + q + 8] = acc2;

        // (4) write next token's slice into the other buffer LATE
        if (t + 1 < TPW) {
            ((float4*)nxt)[lane] = n0;
            ((float4*)nxt)[lane + 64] = n1;
            ((float4*)nxt)[lane + 128] = n2;
            s0 = m0; s1 = m1; s2 = m2; s3 = m3;
        }
    }
}

// ---- fallback tiers ----

__global__ void precompute_g01_nf(const float* __restrict__ core0,
                                  const float* __restrict__ core1,
                                  float* __restrict__ g01) {
    int combo = blockIdx.x;
    int t = threadIdx.x;
    int d0 = combo / 10, d1 = combo % 10;
    int a = t >> 4, r2 = t & 15;
    int a0 = a >> 2, m1 = a & 3;
    float acc = 0.f;
#pragma unroll
    for (int r1 = 0; r1 < 16; ++r1)
        acc += core0[(d0 * 4 + a0) * 16 + r1] *
               core1[((r1 * 10 + d1) * 4 + m1) * 16 + r2];
    g01[combo * 256 + t] = acc;
}

__global__ void precompute_g23_nf(const float* __restrict__ core2,
                                  const float* __restrict__ core3,
                                  float* __restrict__ g23) {
    int combo = blockIdx.x;
    int t = threadIdx.x;
    int d2 = combo / 20, d3 = combo % 20;
#pragma unroll
    for (int i = 0; i < 3; ++i) {
        int flat = t + i * 256;
        int r2 = flat / 48, mc = flat % 48;
        int m2 = mc >> 3, m3 = mc & 7;
        float acc = 0.f;
#pragma unroll
        for (int r3 = 0; r3 < 16; ++r3)
            acc += core2[((r2 * 20 + d2) * 6 + m2) * 16 + r3] *
                   core3[(r3 * 20 + d3) * 8 + m3];
        g23[combo * 768 + flat] = acc;
    }
}

__global__ __launch_bounds__(256) void te_main(const int* __restrict__ x,
                                               const float* __restrict__ g01,
                                               const float* __restrict__ g23,
                                               float* __restrict__ out) {
    int wave = threadIdx.x >> 6;
    int lane = threadIdx.x & 63;
    int tok = blockIdx.x * 4 + wave;
    int idx = x[tok];
    const float* __restrict__ G1 = g01 + (idx / 400) * 256;
    const float* __restrict__ G2 = g23 + (idx % 400) * 768;
    float* __restrict__ o = out + (size_t)tok * 768;
#pragma unroll
    for (int p = 0; p < 3; ++p) {
        int base = (p * 64 + lane) * 4;
        int a = base / 48;
        int mc = base - a * 48;
        const float4* g1v = (const float4*)(G1 + a * 16);
        float4 ca = g1v[0], cb = g1v[1], cc = g1v[2], cd = g1v[3];
        float s[16] = {ca.x, ca.y, ca.z, ca.w, cb.x, cb.y, cb.z, cb.w,
                       cc.x, cc.y, cc.z, cc.w, cd.x, cd.y, cd.z, cd.w};
        float4 acc = {0.f, 0.f, 0.f, 0.f};
#pragma unroll
        for (int r2 = 0; r2 < 16; ++r2) {
            float4 v = *(const float4*)(G2 + r2 * 48 + mc);
            acc.x += s[r2] * v.x;
            acc.y += s[r2] * v.y;
            acc.z += s[r2] * v.z;
            acc.w += s[r2] * v.w;
        }
        *(float4*)(o + base) = acc;
    }
}

__global__ void te_direct(const int* __restrict__ x,
                          const float* __restrict__ core0,
                          const float* __restrict__ core1,
                          const float* __restrict__ core2,
                          const float* __restrict__ core3,
                          float* __restrict__ out) {
    int tok = blockIdx.x;
    int lane = threadIdx.x;
    int idx = x[tok];
    int d0 = idx / 4000;
    int rem = idx - d0 * 4000;
    int d1 = rem / 400;
    rem -= d1 * 400;
    int d2 = rem / 20;
    int d3 = rem - d2 * 20;
    float* o = out + (size_t)tok * 768;
    for (int p = 0; p < 3; ++p) {
        int base = (p * 64 + lane) * 4;
        int a = base / 48;
        int mc = base - a * 48;
        int a0 = a >> 2, m1 = a & 3;
        float s[16];
#pragma unroll
        for (int r2 = 0; r2 < 16; ++r2) {
            float acc = 0.f;
            for (int r1 = 0; r1 < 16; ++r1)
                acc += core0[(d0 * 4 + a0) * 16 + r1] *
                       core1[((r1 * 10 + d1) * 4 + m1) * 16 + r2];
            s[r2] = acc;
        }
        float4 accv = {0.f, 0.f, 0.f, 0.f};
        float* accp = (float*)&accv;
        for (int j = 0; j < 4; ++j) {
            int mcj = mc + j;
            int m2 = mcj >> 3, m3 = mcj & 7;
            float tt = 0.f;
            for (int r2 = 0; r2 < 16; ++r2) {
                float g = 0.f;
                for (int r3 = 0; r3 < 16; ++r3)
                    g += core2[((r2 * 20 + d2) * 6 + m2) * 16 + r3] *
                         core3[(r3 * 20 + d3) * 8 + m3];
                tt += s[r2] * g;
            }
            accp[j] = tt;
        }
        *(float4*)(o + base) = accv;
    }
}

extern "C" void kernel_launch(void* const* d_in, const int* in_sizes, int n_in,
                              void* d_out, int out_size, void* d_ws, size_t ws_size,
                              hipStream_t stream) {
    const int*   x     = (const int*)d_in[0];
    const float* core0 = (const float*)d_in[1];
    const float* core1 = (const float*)d_in[2];
    const float* core2 = (const float*)d_in[3];
    const float* core3 = (const float*)d_in[4];
    float* out = (float*)d_out;

    if (ws_size >= (size_t)TBL_BYTES) {
        float* g01 = (float*)d_ws;
        float* g23 = (float*)((char*)d_ws + G01_BYTES);
        build_tables<<<480, 256, 0, stream>>>(core0, core1, core2, core3, g01, g23);
        // 1024 blocks x 4 waves x 8 tokens = 32768 exactly
        te_stream<<<NTOK / (4 * TPW), 256, 0, stream>>>(x, g01, g23, out);
    } else {
        te_direct<<<NTOK, 64, 0, stream>>>(x, core0, core1, core2, core3, out);
    }
}